// Round 15
// baseline (30.306 us; speedup 1.0000x reference)
//
#include <hip/hip_runtime.h>

// FeatIterpNFMLP: trilinear grid interp (16^3 x 8ch) + MLP 8->64->64->16 (leaky 0.01)
// Round 15: R14 bit-for-bit; ONE change: interp (gathers + feat + bf0 pack) moved
// BEFORE the prolog barrier. Interp has no frag_lds dependence, so its ~300-cyc
// L2 gather latency now overlaps the cooperative prolog and the barrier wait,
// and warps leave the barrier phase-skewed instead of issuing all gathers in
// lockstep (R9's null showed transaction COUNT isn't the wall; R14's win showed
// latency is). Session rules: no d_ws, no forced VGPR caps.

typedef __attribute__((ext_vector_type(8)))  short short8;
typedef __attribute__((ext_vector_type(16))) float f32x16;
typedef __attribute__((ext_vector_type(4)))  int   int4v;

static __device__ __forceinline__ unsigned cvt_pk_bf16(float lo, float hi) {
    unsigned r;
    asm("v_cvt_pk_bf16_f32 %0, %1, %2" : "=v"(r) : "v"(lo), "v"(hi));
    return r;
}
// v_permlane32_swap_b32: swaps low-32-lane half of a with high-32-lane half of b.
static __device__ __forceinline__ void permswap(unsigned &a, unsigned &b) {
    asm("v_permlane32_swap_b32 %0, %1" : "+v"(a), "+v"(b));
}
static __device__ __forceinline__ short8 as_s8(int4v v) {
    return __builtin_bit_cast(short8, v);
}

// leaky-relu one ct's accum pair in place, repack as next-layer B-fragments:
// bfr[kt], k = kt*16 + 8*half + {0..7}.  acc: col(point)=l31, row(j)=(r&3)+8*(r>>2)+4*half.
static __device__ __forceinline__ void relu_pack_ct(f32x16 acc[2], int4v bfr[4]) {
    #pragma unroll
    for (int rt = 0; rt < 2; ++rt)
        #pragma unroll
        for (int r = 0; r < 16; ++r) {
            float a = acc[rt][r];
            acc[rt][r] = fmaxf(a, 0.01f * a);
        }
    #pragma unroll
    for (int kt = 0; kt < 4; ++kt) {
        const int rs = kt >> 1;
        const int base = (kt & 1) * 8;
        unsigned pa0 = cvt_pk_bf16(acc[rs][base + 0], acc[rs][base + 1]);
        unsigned pa1 = cvt_pk_bf16(acc[rs][base + 2], acc[rs][base + 3]);
        unsigned pb0 = cvt_pk_bf16(acc[rs][base + 4], acc[rs][base + 5]);
        unsigned pb1 = cvt_pk_bf16(acc[rs][base + 6], acc[rs][base + 7]);
        permswap(pa0, pb0);
        permswap(pa1, pb1);
        bfr[kt][0] = (int)pa0;
        bfr[kt][1] = (int)pa1;
        bfr[kt][2] = (int)pb0;
        bfr[kt][3] = (int)pb1;
    }
}

__global__ __launch_bounds__(512) void featmlp_mfma(
    const int* __restrict__ idx,
    const float* __restrict__ x,
    const float* __restrict__ emb,
    const float* __restrict__ W0, const float* __restrict__ b0,
    const float* __restrict__ W1, const float* __restrict__ b1,
    const float* __restrict__ Wout, const float* __restrict__ bout,
    float* __restrict__ out)
{
    // fid 0-1: w0f[rt] (b0 folded at k=8) ; fid 2+rt*5+kt: w1f[rt][kt] kt=0..4
    // (b1 folded at k=64) ; fid 12+kt: wof[kt] kt=0..4 (bout folded at k=64)
    __shared__ int4v frag_lds[17 * 64];        // 17 KB, 16B lane stride (conflict-free)

    const int tid  = threadIdx.x;
    const int warp = tid >> 6;                 // 0..7
    const int lane = tid & 63;
    const int half = lane >> 5;
    const int l31  = lane & 31;

    // XCD-chunked swizzle: XCD (bid%8) runs contiguous chunk (bid&7)*128 + bid>>3.
    const int bid = blockIdx.x;
    const int swz = (bid & 7) * 128 + (bid >> 3);            // bijective on [0,1024)
    const int group = swz * 8 + warp;                        // 8192 groups
    const long pbase = (long)group * 64;
    const int  b  = group >> 7;                              // 128 groups / example

    const float* __restrict__ g = emb + ((long)idx[b] << 15);

    // ---- x loads issued first ----
    const long p = pbase + lane;
    const float x0 = x[p * 3 + 0];
    const float x1 = x[p * 3 + 1];
    const float x2 = x[p * 3 + 2];

    // ---- interp addressing + gather issue (BEFORE prolog: no frag_lds dep) ----
    // No masks/clamps: x = -0.5 + k*2^-23 => x+0.5 exact => ix in [0,14], in-bounds.
    const float lx = (x0 + 0.5f) * 15.0f;
    const float ly = (x1 + 0.5f) * 15.0f;
    const float lz = (x2 + 0.5f) * 15.0f;
    const float fx = floorf(lx), fy = floorf(ly), fz = floorf(lz);
    const float wx1 = lx - fx, wy1 = ly - fy, wz1 = lz - fz;
    const float wx0 = 1.0f - wx1, wy0 = 1.0f - wy1, wz0 = 1.0f - wz1;
    const int ix = (int)fx, iy = (int)fy, iz = (int)fz;
    const int vbase = ((iz * 16) + iy) * 16 + ix;

    float feat[8];
    #pragma unroll
    for (int c = 0; c < 8; ++c) feat[c] = 0.0f;
    #pragma unroll
    for (int dz = 0; dz < 2; ++dz) {
        const float wz = dz ? wz1 : wz0;
        #pragma unroll
        for (int dy = 0; dy < 2; ++dy) {
            const float wzy = wz * (dy ? wy1 : wy0);
            #pragma unroll
            for (int dx = 0; dx < 2; ++dx) {
                const float w = wzy * (dx ? wx1 : wx0);
                const float4* v = (const float4*)(g + (long)(vbase + dz * 256 + dy * 16 + dx) * 8);
                const float4 v0 = v[0];
                const float4 v1 = v[1];
                feat[0] += w * v0.x; feat[1] += w * v0.y;
                feat[2] += w * v0.z; feat[3] += w * v0.w;
                feat[4] += w * v1.x; feat[5] += w * v1.y;
                feat[6] += w * v1.z; feat[7] += w * v1.w;
            }
        }
    }

    // ---- feat -> layer-0 B-fragments (also before barrier; permlane only) ----
    int4v bf0[2];
    #pragma unroll
    for (int m = 0; m < 4; ++m) {
        unsigned a = cvt_pk_bf16(feat[2 * m], feat[2 * m + 1]);
        unsigned z = (m == 0) ? 0x00003f80u : 0u;    // bf16 1.0 at k=8 (bias row)
        permswap(a, z);
        bf0[0][m] = (int)a;
        bf0[1][m] = (int)z;
    }

    // ---- cooperative prolog: 17 fragment families over 8 warps (<=3 each) ----
    // A[row=j][k] = W[k][j]; lane holds row j = rt*32 + l31, k = kt*16 + half*8 + 2m+{0,1}
    for (int fid = warp; fid < 17; fid += 8) {
        int4v f;
        if (fid < 2) {                         // w0f rt=fid; b0 folded at k=8
            const int j = fid * 32 + l31;
            if (half == 0) {
                #pragma unroll
                for (int m = 0; m < 4; ++m)
                    f[m] = (int)cvt_pk_bf16(W0[(2 * m) * 64 + j], W0[(2 * m + 1) * 64 + j]);
            } else {
                f[0] = (int)cvt_pk_bf16(b0[j], 0.0f);       // k=8 -> bias row
                f[1] = 0; f[2] = 0; f[3] = 0;
            }
        } else if (fid < 12) {                 // w1f rt=(fid-2)/5, kt=(fid-2)%5
            const int t = fid - 2;
            const int rt = t / 5, kt = t % 5;
            const int j = rt * 32 + l31;
            if (kt < 4) {
                #pragma unroll
                for (int m = 0; m < 4; ++m) {
                    const int k = kt * 16 + half * 8 + 2 * m;
                    f[m] = (int)cvt_pk_bf16(W1[k * 64 + j], W1[(k + 1) * 64 + j]);
                }
            } else {                           // kt=4: k=64 -> b1 row
                f[0] = half ? 0 : (int)cvt_pk_bf16(b1[j], 0.0f);
                f[1] = 0; f[2] = 0; f[3] = 0;
            }
        } else {                               // wof kt=fid-12 (rows j>=16 unused, clamp)
            const int kt = fid - 12;
            const int jo = l31 < 15 ? l31 : 15;
            if (kt < 4) {
                #pragma unroll
                for (int m = 0; m < 4; ++m) {
                    const int k = kt * 16 + half * 8 + 2 * m;
                    f[m] = (int)cvt_pk_bf16(Wout[k * 16 + jo], Wout[(k + 1) * 16 + jo]);
                }
            } else {                           // kt=4: k=64 -> bout row
                f[0] = half ? 0 : (int)cvt_pk_bf16(bout[jo], 0.0f);
                f[1] = 0; f[2] = 0; f[3] = 0;
            }
        }
        frag_lds[fid * 64 + lane] = f;
    }

    __syncthreads();   // fragments ready (written once; no later writes)

    // constant B-fragment for the K=80 bias tile (row 64 == 1.0): lanes<32, m0 low.
    int4v b1x;
    b1x[0] = half ? 0 : 0x00003f80;
    b1x[1] = 0; b1x[2] = 0; b1x[3] = 0;

    f32x16 zc;                                        // shared zero C-operand
    #pragma unroll
    for (int i = 0; i < 16; ++i) zc[i] = 0.0f;

    // ================= ct-sequential MLP (32 points per pass) =================
    #pragma unroll
    for (int ct = 0; ct < 2; ++ct) {
        // ---- layer 0 ----
        f32x16 acc0[2];
        #pragma unroll
        for (int rt = 0; rt < 2; ++rt) {
            const int4v wf = frag_lds[rt * 64 + lane];
            acc0[rt] = __builtin_amdgcn_mfma_f32_32x32x16_bf16(
                as_s8(wf), as_s8(bf0[ct]), zc, 0, 0, 0);
        }

        int4v b1f[4];
        relu_pack_ct(acc0, b1f);

        // ---- layer 1 (K=80: 4 data tiles + bias tile) ----
        f32x16 acc1[2];
        #pragma unroll
        for (int rt = 0; rt < 2; ++rt) {
            f32x16 a = zc;
            #pragma unroll
            for (int kt = 0; kt < 4; ++kt) {
                const int4v wf = frag_lds[(2 + rt * 5 + kt) * 64 + lane];
                a = __builtin_amdgcn_mfma_f32_32x32x16_bf16(
                    as_s8(wf), as_s8(b1f[kt]), a, 0, 0, 0);
            }
            const int4v wb = frag_lds[(2 + rt * 5 + 4) * 64 + lane];
            acc1[rt] = __builtin_amdgcn_mfma_f32_32x32x16_bf16(
                as_s8(wb), as_s8(b1x), a, 0, 0, 0);
        }

        int4v b2f[4];
        relu_pack_ct(acc1, b2f);

        // ---- layer 2 (K=80; rows j<16 valid) ----
        f32x16 a = zc;
        #pragma unroll
        for (int kt = 0; kt < 4; ++kt) {
            const int4v wf = frag_lds[(12 + kt) * 64 + lane];
            a = __builtin_amdgcn_mfma_f32_32x32x16_bf16(
                as_s8(wf), as_s8(b2f[kt]), a, 0, 0, 0);
        }
        const int4v wb = frag_lds[16 * 64 + lane];
        a = __builtin_amdgcn_mfma_f32_32x32x16_bf16(
            as_s8(wb), as_s8(b1x), a, 0, 0, 0);

        // j = (r&3) + 8*(r>>2) + 4*half ; point = pbase + ct*32 + l31
        float* o = out + (pbase + ct * 32 + l31) * 16;
        *(float4*)(o + half * 4)     = make_float4(a[0], a[1], a[2], a[3]);
        *(float4*)(o + 8 + half * 4) = make_float4(a[4], a[5], a[6], a[7]);
    }
}

extern "C" void kernel_launch(void* const* d_in, const int* in_sizes, int n_in,
                              void* d_out, int out_size, void* d_ws, size_t ws_size,
                              hipStream_t stream) {
    const int*   idx  = (const int*)  d_in[0];
    const float* x    = (const float*)d_in[1];
    const float* emb  = (const float*)d_in[2];
    const float* W0   = (const float*)d_in[3];
    const float* b0   = (const float*)d_in[4];
    const float* W1   = (const float*)d_in[5];
    const float* b1   = (const float*)d_in[6];
    const float* Wout = (const float*)d_in[7];
    const float* bout = (const float*)d_in[8];
    float* out = (float*)d_out;

    // 8192 groups / 8 per block = 1024 blocks of 512 threads
    featmlp_mfma<<<1024, 512, 0, stream>>>(idx, x, emb, W0, b0, W1, b1,
                                           Wout, bout, out);
}